// Round 7
// baseline (226.551 us; speedup 1.0000x reference)
//
#include <hip/hip_runtime.h>
#include <hip/hip_bf16.h>

// SrnmSpmm: out[b,s,n] = sum_k x[b,s,keep[k]] * values[n,k] + bias[n]
// keep: cols {8i, 8i+2} of D_IN=4096 -> K=1024. M = B*S = 16384, N = 4096.
//
// R7: single-barrier phases: {vmcnt(10); BAR; STAGE; ds_reads; MFMA} so
// LDS-reads of some waves overlap MFMA of others (previous 2-bar structure
// serialized them: 1450 cyc/phase vs ~620 MFMA content). vmcnt is per-phase
// and counted (10 = exact for the 7-slot prefetch distance). Post-epilogue
// iterations use vmcnt(63) so C-stores drain in background.

#define M_TOTAL 16384
#define DIN     4096
#define KDIM    1024
#define NDIM    4096

typedef unsigned short u16;
typedef unsigned int   u32;
typedef __bf16 bf16x8 __attribute__((ext_vector_type(8)));
typedef float  f32x4  __attribute__((ext_vector_type(4)));

typedef const void __attribute__((address_space(1)))* gp_t;
typedef void __attribute__((address_space(3)))*       lp_t;

__device__ __forceinline__ u16 f2bf(float f) {
    u32 u = __float_as_uint(f);
    u += 0x7FFFu + ((u >> 16) & 1u);   // round-to-nearest-even
    return (u16)(u >> 16);
}
__device__ __forceinline__ u32 pack2(float a, float b) {
    return (u32)f2bf(a) | ((u32)f2bf(b) << 16);
}

// Pass 1: blocks [0,4096): compact x — each lane owns one 64B line (2 x
// 8-block): f32x4 @ +0 and @ +32B -> uint2 (kept cols 0,2). NT loads.
// Blocks [4096,6144): cast values, 8 floats/lane -> uint4. NT loads.
__global__ void prep_kernel(const float* __restrict__ x, uint2* __restrict__ xg2,
                            const float* __restrict__ vals, uint4* __restrict__ vb4) {
    const int tid = threadIdx.x;
    if (blockIdx.x < 4096) {
        int i = blockIdx.x * 256 + tid;
        const int stride = 4096 * 256;     // 4,194,304 lines = 4*stride exact
#pragma unroll
        for (int it = 0; it < 4; ++it, i += stride) {
            const f32x4* p = (const f32x4*)(x + (size_t)i * 16);
            f32x4 f0 = __builtin_nontemporal_load(p);
            f32x4 f1 = __builtin_nontemporal_load(p + 2);
            xg2[i] = make_uint2(pack2(f0.x, f0.z), pack2(f1.x, f1.z));
        }
    } else {
        const int i = (blockIdx.x - 4096) * 256 + tid;   // [0, 524288)
        const f32x4* p = (const f32x4*)(vals + (size_t)i * 8);
        f32x4 a = __builtin_nontemporal_load(p);
        f32x4 b = __builtin_nontemporal_load(p + 1);
        vb4[i] = make_uint4(pack2(a.x, a.y), pack2(a.z, a.w),
                            pack2(b.x, b.y), pack2(b.z, b.w));
    }
}

// ---------------- persistent 256x256 bf16 GEMM, single-bar phases ----------
// 512 threads = 8 waves (2M x 4N); wave tile 128x64. K-tile 64 (2 K-halves).
// Half-tile (slot) = 256 rows x 32 cols bf16 = 16 KiB = 2 gload_lds.
// LDS 128 KiB: A[dbuf][kh] @ (2d+kh)*16K, B @ +64K. st_16x32 swizzle applied
// on global SOURCE (gload dest linear) and on ds_read addr.
// Slot s staged 7 phases before its first read; vmcnt(10) = all but the 5
// newest STAGEs (10 instr) landed => the 2 slots this phase reads landed.

#define LDSA(d, kh) (((d) * 2 + (kh)) * 16384)
#define LDSB(d, kh) (65536 + ((d) * 2 + (kh)) * 16384)

#define LOADA(d, kh, mh) { _Pragma("unroll") \
    for (int m_ = 0; m_ < 4; ++m_) \
        af[m_] = *(const bf16x8*)(lds + LDSA(d, kh) + (wr * 8 + (mh) * 4 + m_) * 1024 + fl_off); }

#define LOADB(d, kh) { _Pragma("unroll") \
    for (int n_ = 0; n_ < 4; ++n_) \
        bfr[n_] = *(const bf16x8*)(lds + LDSB(d, kh) + (wc * 4 + n_) * 1024 + fl_off); }

#define MFMA16(mh) { \
    __builtin_amdgcn_s_setprio(1); \
    _Pragma("unroll") for (int m_ = 0; m_ < 4; ++m_) \
    _Pragma("unroll") for (int n_ = 0; n_ < 4; ++n_) \
        acc[(mh) * 4 + m_][n_] = __builtin_amdgcn_mfma_f32_16x16x32_bf16( \
            af[m_], bfr[n_], acc[(mh) * 4 + m_][n_], 0, 0, 0); \
    __builtin_amdgcn_s_setprio(0); }

#define BAR() __builtin_amdgcn_s_barrier()
#define VMCNT10() asm volatile("s_waitcnt vmcnt(10)" ::: "memory")
#define VMCNT63() asm volatile("s_waitcnt vmcnt(63)" ::: "memory")

// Phase: wait slots readable (all waves, via BAR) -> overwrite-safe STAGE
// (region's readers all pre-BAR) -> ds_reads + MFMA in ONE region (overlap).
#define PH(W, STG, LDS_, mh) { W; BAR(); STG; LDS_; MFMA16(mh); }

#define ITER(As_, Sb, W) { \
  PH(W, STAGE(As_, (Sb) + 0), LOADB(0,0); LOADA(0,0,0), 0) \
  PH(W, STAGE(As_, (Sb) + 1), LOADA(0,0,1),             1) \
  PH(W, STAGE(As_, (Sb) + 2), LOADB(0,1); LOADA(0,1,0), 0) \
  PH(W, STAGE(As_, (Sb) + 3), LOADA(0,1,1),             1) \
  PH(W, STAGE(As_, (Sb) + 4), LOADB(1,0); LOADA(1,0,0), 0) \
  PH(W, STAGE(As_, (Sb) + 5), LOADA(1,0,1),             1) \
  PH(W, STAGE(As_, (Sb) + 6), LOADB(1,1); LOADA(1,1,0), 0) \
  PH(W, STAGE(As_, (Sb) + 7), LOADA(1,1,1),             1) }

// Tail iter of a row-tile: stages slot 63 then next tile's slots 0..6.
#define TAIL_ITER(Ar_, An_) { \
  PH(VMCNT10(), STAGE(Ar_, 63), LOADB(0,0); LOADA(0,0,0), 0) \
  PH(VMCNT10(), STAGE(An_, 0),  LOADA(0,0,1),             1) \
  PH(VMCNT10(), STAGE(An_, 1),  LOADB(0,1); LOADA(0,1,0), 0) \
  PH(VMCNT10(), STAGE(An_, 2),  LOADA(0,1,1),             1) \
  PH(VMCNT10(), STAGE(An_, 3),  LOADB(1,0); LOADA(1,0,0), 0) \
  PH(VMCNT10(), STAGE(An_, 4),  LOADA(1,0,1),             1) \
  PH(VMCNT10(), STAGE(An_, 5),  LOADB(1,1); LOADA(1,1,0), 0) \
  PH(VMCNT10(), STAGE(An_, 6),  LOADA(1,1,1),             1) }

__global__ __launch_bounds__(512, 2) void gemm_kernel(
    const u16* __restrict__ A, const u16* __restrict__ Bv,
    const float* __restrict__ bias, float* __restrict__ C)
{
    __shared__ __align__(1024) char lds[131072];

    const int tid  = threadIdx.x;
    const int lane = tid & 63;
    const int wid  = tid >> 6;
    const int wr   = wid >> 2;      // 0..1
    const int wc   = wid & 3;       // 0..3
    const int lrow = lane & 15;
    const int lg   = lane >> 4;     // 0..3

    // Persistent mapping: XCD (bb&7) covers btm {8c..8c+7}; btn fixed/block.
    const int bb   = blockIdx.x;
    const int btm0 = (bb & 7) * 8 + (bb >> 7);
    const int btn  = (bb >> 3) & 15;

    // Staging source (pre-swizzled global addr; LDS dest linear).
    const int st_r0 = wid * 16 + (lane >> 2);
    const int st_ck = ((lane & 3) * 8) ^ ((lane & 32) >> 1);
    const u16* A0  = A  + (size_t)(btm0 * 256 + st_r0) * KDIM + st_ck;
    const u16* Bs0 = Bv + (size_t)(btn  * 256 + st_r0) * KDIM + st_ck;
    const int dst0 = tid * 16;

    // Fragment ds_read offset within a half-tile (subtiled + swizzled).
    const int fl_off = lrow * 64 + ((lg * 16) ^ (((lrow >> 3) & 1) << 5));

    // half-tile slot s: kt=s>>2, j=s&3 (0=A.kh0,1=B.kh0,2=A.kh1,3=B.kh1)
    auto STAGE = [&](const u16* as_, int s) {
        const int kt = s >> 2, j = s & 3;
        const int d = kt & 1, kh = (j >> 1) & 1;
        const int ko = kt * 64 + kh * 32;
        const u16* src = (j & 1) ? Bs0 : as_;
        const int base = ((j & 1) ? 65536 : 0) + (d * 2 + kh) * 16384;
        __builtin_amdgcn_global_load_lds((gp_t)(src + ko),
            (lp_t)(lds + base + dst0), 16, 0, 0);
        __builtin_amdgcn_global_load_lds((gp_t)(src + 128 * KDIM + ko),
            (lp_t)(lds + base + 8192 + dst0), 16, 0, 0);
    };

    // bias is loop-invariant (btn fixed): load once.
    const int c_col0 = btn * 256 + wc * 64 + lrow;
    float bvr[4];
#pragma unroll
    for (int n = 0; n < 4; ++n) bvr[n] = bias[c_col0 + n * 16];

    f32x4 acc[8][4] = {};
    bf16x8 af[4], bfr[4];

    // Prologue: stage slots 0..6 of tile 0 (7 slots ahead; first phase's
    // vmcnt(10) then guarantees slots 0,1).
    STAGE(A0, 0); STAGE(A0, 1); STAGE(A0, 2); STAGE(A0, 3);
    STAGE(A0, 4); STAGE(A0, 5); STAGE(A0, 6);

#pragma unroll 1
    for (int r = 0; r < 4; ++r) {
        const u16* Ar = A0 + (size_t)r * 512 * KDIM;
        const u16* An = (r < 3) ? (Ar + 512 * KDIM) : Ar;  // r=3: dummy re-stage

        // First iter after an epilogue: vmcnt(63) (needed slots pre-date the
        // 128 stores, so >=63 newer ops guarantee them; stores drain in bg).
        if (r == 0) { ITER(Ar, 7, VMCNT10()) }
        else        { ITER(Ar, 7, VMCNT63()) }

#pragma unroll 1
        for (int u = 1; u < 7; ++u) {
            ITER(Ar, 8 * u + 7, VMCNT10())
        }
        TAIL_ITER(Ar, An)

        // Epilogue tile r: NT stores (don't evict xg/vb from L2/L3).
        const int c_row0 = (btm0 + 2 * r) * 256 + wr * 128 + lg * 4;
#pragma unroll
        for (int mi = 0; mi < 8; ++mi) {
            const int row = c_row0 + (mi >> 2) * 64 + (mi & 3) * 16;
#pragma unroll
            for (int n = 0; n < 4; ++n) {
#pragma unroll
                for (int j = 0; j < 4; ++j)
                    __builtin_nontemporal_store(acc[mi][n][j] + bvr[n],
                        &C[(size_t)(row + j) * NDIM + c_col0 + n * 16]);
                acc[mi][n] = (f32x4){0.f, 0.f, 0.f, 0.f};
            }
        }
    }
}

extern "C" void kernel_launch(void* const* d_in, const int* in_sizes, int n_in,
                              void* d_out, int out_size, void* d_ws, size_t ws_size,
                              hipStream_t stream) {
    const float* x      = (const float*)d_in[0];
    const float* values = (const float*)d_in[1];
    const float* bias   = (const float*)d_in[2];
    float* out = (float*)d_out;

    // ws: xg bf16 [16384][1024] = 32 MB @ 0; values bf16 [4096][1024] @ 32 MB
    u16* xg = (u16*)d_ws;
    u16* vb = (u16*)((char*)d_ws + ((size_t)32 << 20));

    prep_kernel<<<6144, 256, 0, stream>>>(x, (uint2*)xg, values, (uint4*)vb);
    gemm_kernel<<<256, 512, 0, stream>>>(xg, vb, bias, out);
}